// Round 1
// baseline (752.835 us; speedup 1.0000x reference)
//
#include <hip/hip_runtime.h>
#include <math.h>

#define NEG_SLOPE 0.1f

constexpr int Bn = 512;
constexpr int Sn = 256;
constexpr int Dn = 256;
constexpr int Mn = Bn * Sn; // 131072

// ---------------------------------------------------------------------------
// Kernel 0: transpose W1 (e,d) -> W1T (d,e) so GEMM B-reads are row-contiguous
// ---------------------------------------------------------------------------
__global__ __launch_bounds__(256) void k_transpose(const float* __restrict__ w1,
                                                   float* __restrict__ w1t) {
  int d = blockIdx.x;
  int e = threadIdx.x;
  // write coalesced, read strided (tiny 256KB matrix, once per launch)
  w1t[d * 256 + e] = w1[e * 256 + d];
}

// ---------------------------------------------------------------------------
// Kernel 1: Wh[m, e] = sum_d x[m, d] * W1T[d, e] + b1[e]
// 64x64 tile per 256-thread block, 4x4 microtile per thread, K-step 16.
// ---------------------------------------------------------------------------
__global__ __launch_bounds__(256) void k_gemm1(const float* __restrict__ x,
                                               const float* __restrict__ w1t,
                                               const float* __restrict__ b1,
                                               float* __restrict__ wh) {
  __shared__ float As[16][68]; // [k][m], stride 68 keeps float4 alignment
  __shared__ float Bs[16][68]; // [k][n]
  const int tid = threadIdx.x;
  const int row0 = blockIdx.y * 64;
  const int col0 = blockIdx.x * 64;
  const int tm = tid >> 4;          // 0..15
  const int tn = tid & 15;          // 0..15
  const int la_r = tid >> 2;        // 0..63
  const int la_k = (tid & 3) << 2;  // 0,4,8,12
  const int lb_k = tid >> 4;        // 0..15
  const int lb_c = (tid & 15) << 2; // 0..60

  float acc[4][4] = {};

  for (int k0 = 0; k0 < 256; k0 += 16) {
    float4 av = *(const float4*)(x + (size_t)(row0 + la_r) * 256 + (k0 + la_k));
    float4 bv = *(const float4*)(w1t + (size_t)(k0 + lb_k) * 256 + (col0 + lb_c));
    __syncthreads(); // previous iteration's reads complete before overwrite
    As[la_k + 0][la_r] = av.x;
    As[la_k + 1][la_r] = av.y;
    As[la_k + 2][la_r] = av.z;
    As[la_k + 3][la_r] = av.w;
    *(float4*)&Bs[lb_k][lb_c] = bv;
    __syncthreads();
#pragma unroll
    for (int kk = 0; kk < 16; ++kk) {
      float4 a = *(float4*)&As[kk][tm << 2];
      float4 b = *(float4*)&Bs[kk][tn << 2];
      acc[0][0] += a.x * b.x; acc[0][1] += a.x * b.y; acc[0][2] += a.x * b.z; acc[0][3] += a.x * b.w;
      acc[1][0] += a.y * b.x; acc[1][1] += a.y * b.y; acc[1][2] += a.y * b.z; acc[1][3] += a.y * b.w;
      acc[2][0] += a.z * b.x; acc[2][1] += a.z * b.y; acc[2][2] += a.z * b.z; acc[2][3] += a.z * b.w;
      acc[3][0] += a.w * b.x; acc[3][1] += a.w * b.y; acc[3][2] += a.w * b.z; acc[3][3] += a.w * b.w;
    }
  }

  float4 bb = *(const float4*)(b1 + col0 + (tn << 2));
#pragma unroll
  for (int mi = 0; mi < 4; ++mi) {
    float4 o;
    o.x = acc[mi][0] + bb.x;
    o.y = acc[mi][1] + bb.y;
    o.z = acc[mi][2] + bb.z;
    o.w = acc[mi][3] + bb.w;
    *(float4*)(wh + (size_t)(row0 + (tm << 2) + mi) * 256 + col0 + (tn << 2)) = o;
  }
}

// ---------------------------------------------------------------------------
// Kernel 2: e_l[m] = Wh[m,:] . a_w[:256] ; e_r[m] = Wh[m,:] . a_w[256:512]
// One wave (64 lanes) per row; float4 loads; butterfly shuffle reduce.
// ---------------------------------------------------------------------------
__global__ __launch_bounds__(256) void k_elr(const float* __restrict__ wh,
                                             const float* __restrict__ a_w,
                                             float* __restrict__ e_l,
                                             float* __restrict__ e_r) {
  const int wave = threadIdx.x >> 6;
  const int lane = threadIdx.x & 63;
  const int row = blockIdx.x * 4 + wave;
  float4 h = *(const float4*)(wh + (size_t)row * 256 + lane * 4);
  float4 al = *(const float4*)(a_w + lane * 4);
  float4 ar = *(const float4*)(a_w + 256 + lane * 4);
  float sl = h.x * al.x + h.y * al.y + h.z * al.z + h.w * al.w;
  float sr = h.x * ar.x + h.y * ar.y + h.z * ar.z + h.w * ar.w;
#pragma unroll
  for (int o = 32; o > 0; o >>= 1) {
    sl += __shfl_xor(sl, o);
    sr += __shfl_xor(sr, o);
  }
  if (lane == 0) {
    e_l[row] = sl;
    e_r[row] = sr;
  }
}

// ---------------------------------------------------------------------------
// Kernel 3: per (b, 32-row i-tile): scores -> leaky -> +pos -> softmax(j)
//           -> agg = w @ Wh_b -> elu -> out
// 256 threads. LDS w[32][260] (stride 260: float4-aligned rows).
// Aggregation: wave ig owns i-rows ig*8..ig*8+7; w-reads are wave-broadcast.
// ---------------------------------------------------------------------------
__global__ __launch_bounds__(256) void k_attn(const float* __restrict__ wh,
                                              const float* __restrict__ pos,
                                              const float* __restrict__ e_l,
                                              const float* __restrict__ e_r,
                                              const float* __restrict__ a_b,
                                              float* __restrict__ out) {
  __shared__ float w[32][260];
  __shared__ float er_s[256];
  __shared__ float el_s[32];

  const int b = blockIdx.y;
  const int i0 = blockIdx.x * 32;
  const int t = threadIdx.x;
  const float ab = a_b[0];

  er_s[t] = e_r[b * 256 + t];
  if (t < 32) el_s[t] = e_l[b * 256 + i0 + t];
  __syncthreads();

  // scores: s = leakyrelu(e_l[i] + e_r[j] + ab) + pos[b, i0+i, j]
  const float* posb = pos + ((size_t)b * 256 + i0) * 256;
#pragma unroll 4
  for (int i = 0; i < 32; ++i) {
    float s = el_s[i] + er_s[t] + ab;
    s = (s >= 0.0f) ? s : NEG_SLOPE * s;
    s += posb[(size_t)i * 256 + t];
    w[i][t] = s;
  }
  __syncthreads();

  // softmax over j for each row; wave wv handles rows wv, wv+4, ...
  const int wave = t >> 6;
  const int lane = t & 63;
  for (int i = wave; i < 32; i += 4) {
    float4 v = *(float4*)&w[i][lane * 4];
    float m = fmaxf(fmaxf(v.x, v.y), fmaxf(v.z, v.w));
#pragma unroll
    for (int o = 32; o > 0; o >>= 1) m = fmaxf(m, __shfl_xor(m, o));
    float e0 = __expf(v.x - m);
    float e1 = __expf(v.y - m);
    float e2 = __expf(v.z - m);
    float e3 = __expf(v.w - m);
    float ssum = e0 + e1 + e2 + e3;
#pragma unroll
    for (int o = 32; o > 0; o >>= 1) ssum += __shfl_xor(ssum, o);
    float inv = 1.0f / ssum;
    float4 r;
    r.x = e0 * inv; r.y = e1 * inv; r.z = e2 * inv; r.w = e3 * inv;
    *(float4*)&w[i][lane * 4] = r;
  }
  __syncthreads();

  // aggregation: wave ig owns i-rows ig*8..ig*8+7; lane owns 4 d-columns
  const int ig = t >> 6;
  const int d4 = (t & 63) * 4;
  const float* whb = wh + (size_t)b * 256 * 256;
  float acc[8][4] = {};
  for (int j = 0; j < 256; j += 4) {
    float4 h0 = *(const float4*)(whb + (size_t)(j + 0) * 256 + d4);
    float4 h1 = *(const float4*)(whb + (size_t)(j + 1) * 256 + d4);
    float4 h2 = *(const float4*)(whb + (size_t)(j + 2) * 256 + d4);
    float4 h3 = *(const float4*)(whb + (size_t)(j + 3) * 256 + d4);
#pragma unroll
    for (int ii = 0; ii < 8; ++ii) {
      float4 wv = *(float4*)&w[ig * 8 + ii][j]; // wave-broadcast, conflict-free
      acc[ii][0] += wv.x * h0.x + wv.y * h1.x + wv.z * h2.x + wv.w * h3.x;
      acc[ii][1] += wv.x * h0.y + wv.y * h1.y + wv.z * h2.y + wv.w * h3.y;
      acc[ii][2] += wv.x * h0.z + wv.y * h1.z + wv.z * h2.z + wv.w * h3.z;
      acc[ii][3] += wv.x * h0.w + wv.y * h1.w + wv.z * h2.w + wv.w * h3.w;
    }
  }

  // elu + store
#pragma unroll
  for (int ii = 0; ii < 8; ++ii) {
    float4 o;
    o.x = (acc[ii][0] > 0.0f) ? acc[ii][0] : (__expf(acc[ii][0]) - 1.0f);
    o.y = (acc[ii][1] > 0.0f) ? acc[ii][1] : (__expf(acc[ii][1]) - 1.0f);
    o.z = (acc[ii][2] > 0.0f) ? acc[ii][2] : (__expf(acc[ii][2]) - 1.0f);
    o.w = (acc[ii][3] > 0.0f) ? acc[ii][3] : (__expf(acc[ii][3]) - 1.0f);
    *(float4*)(out + ((size_t)b * 256 + i0 + ig * 8 + ii) * 256 + d4) = o;
  }
}

// ---------------------------------------------------------------------------
extern "C" void kernel_launch(void* const* d_in, const int* in_sizes, int n_in,
                              void* d_out, int out_size, void* d_ws, size_t ws_size,
                              hipStream_t stream) {
  const float* x   = (const float*)d_in[0];
  const float* pos = (const float*)d_in[1];
  const float* w1  = (const float*)d_in[2];
  const float* b1  = (const float*)d_in[3];
  const float* a_w = (const float*)d_in[4];
  const float* a_b = (const float*)d_in[5];
  float* out = (float*)d_out;

  float* ws  = (float*)d_ws;
  float* w1t = ws;                         // 65536 floats
  float* wh  = ws + 65536;                 // Mn*Dn floats (128 MiB)
  float* e_l = wh + (size_t)Mn * Dn;       // Mn floats
  float* e_r = e_l + Mn;                   // Mn floats

  k_transpose<<<dim3(256), dim3(256), 0, stream>>>(w1, w1t);
  k_gemm1<<<dim3(4, Mn / 64), dim3(256), 0, stream>>>(x, w1t, b1, wh);
  k_elr<<<dim3(Mn / 4), dim3(256), 0, stream>>>(wh, a_w, e_l, e_r);
  k_attn<<<dim3(Sn / 32, Bn), dim3(256), 0, stream>>>(wh, pos, e_l, e_r, a_b, out);
}

// Round 2
// 448.804 us; speedup vs baseline: 1.6774x; 1.6774x over previous
//
#include <hip/hip_runtime.h>
#include <math.h>

#define NEG_SLOPE 0.1f

constexpr int Bn = 512;
constexpr int Sn = 256;
constexpr int Dn = 256;
constexpr int Mn = Bn * Sn; // 131072

typedef short bf16x8 __attribute__((ext_vector_type(8))); // 8 bf16 in 4 VGPRs
typedef float f32x4 __attribute__((ext_vector_type(4)));

__device__ inline ushort f2bf(float f) { // round-to-nearest-even bf16 bits
  uint u = __float_as_uint(f);
  uint r = u + 0x7FFFu + ((u >> 16) & 1u);
  return (ushort)(r >> 16);
}
__device__ inline float bf2f(ushort h) { return __uint_as_float(((uint)h) << 16); }

// ---------------------------------------------------------------------------
// Kernel 0: W1 (fp32 [e][d]) -> bf16 hi/lo pair, same layout.
// b_frag for gemm1 reads 8 consecutive d at fixed e => original layout works.
// ---------------------------------------------------------------------------
__global__ __launch_bounds__(256) void k_prep(const float* __restrict__ w1,
                                              ushort* __restrict__ w1h,
                                              ushort* __restrict__ w1l) {
  int idx = blockIdx.x * 256 + threadIdx.x;
  float v = w1[idx];
  ushort h = f2bf(v);
  w1h[idx] = h;
  w1l[idx] = f2bf(v - bf2f(h));
}

// ---------------------------------------------------------------------------
// Kernel 1: Wh = x @ W1^T + b1 via bf16 split MFMA (3 terms).
// Block: 64 rows (one b), N=256 full width, 4 waves each owning 64 cols.
// Fused: e_l/e_r row dots (frag reduce + butterfly), Wh^T bf16 write via LDS
// transpose ([b][d][s] layout = aggregation B-operand layout). No fp32 Wh.
// ---------------------------------------------------------------------------
__global__ __launch_bounds__(256) void k_gemm1(const float* __restrict__ x,
                                               const ushort* __restrict__ w1h,
                                               const ushort* __restrict__ w1l,
                                               const float* __restrict__ b1,
                                               const float* __restrict__ a_w,
                                               ushort* __restrict__ whT,
                                               float* __restrict__ e_l,
                                               float* __restrict__ e_r) {
  // union: A-staging (2 * 64*72 = 9216 ushort) | transpose buf (256*72 = 18432)
  __shared__ __align__(16) ushort smem[256 * 72];
  __shared__ float epart[2][4][64];
  ushort* Ah = smem;            // [64][72] bf16 hi of x chunk
  ushort* Al = smem + 64 * 72;  // [64][72] bf16 lo

  const int t = threadIdx.x;
  const int wave = t >> 6, lane = t & 63;
  const int q = lane >> 4, c = lane & 15;
  const int row0 = blockIdx.x * 64;
  const int n0 = wave * 64;

  f32x4 acc[4][4];
#pragma unroll
  for (int mi = 0; mi < 4; ++mi)
#pragma unroll
    for (int nt = 0; nt < 4; ++nt) acc[mi][nt] = (f32x4){0.f, 0.f, 0.f, 0.f};

  const int r = t >> 2;            // 0..63 (staging row)
  const int kq = (t & 3) << 4;     // 0,16,32,48
  const float* xrow = x + (size_t)(row0 + r) * 256 + kq;

  for (int k0 = 0; k0 < 256; k0 += 64) {
    float4 v0 = *(const float4*)(xrow + k0 + 0);
    float4 v1 = *(const float4*)(xrow + k0 + 4);
    float4 v2 = *(const float4*)(xrow + k0 + 8);
    float4 v3 = *(const float4*)(xrow + k0 + 12);
    __syncthreads(); // prior chunk's LDS reads complete
    {
      float vv[16] = {v0.x, v0.y, v0.z, v0.w, v1.x, v1.y, v1.z, v1.w,
                      v2.x, v2.y, v2.z, v2.w, v3.x, v3.y, v3.z, v3.w};
#pragma unroll
      for (int j = 0; j < 4; ++j) {
        ushort4 h, l;
        ushort* hp = (ushort*)&h;
        ushort* lp = (ushort*)&l;
#pragma unroll
        for (int e = 0; e < 4; ++e) {
          float f = vv[j * 4 + e];
          ushort hb = f2bf(f);
          hp[e] = hb;
          lp[e] = f2bf(f - bf2f(hb));
        }
        *(ushort4*)&Ah[r * 72 + kq + j * 4] = h;
        *(ushort4*)&Al[r * 72 + kq + j * 4] = l;
      }
    }
    __syncthreads();

#pragma unroll
    for (int kk = 0; kk < 64; kk += 32) {
      bf16x8 bh[4], bl[4];
#pragma unroll
      for (int nt = 0; nt < 4; ++nt) {
        size_t off = (size_t)(n0 + nt * 16 + c) * 256 + (k0 + kk) + q * 8;
        bh[nt] = *(const bf16x8*)(w1h + off);
        bl[nt] = *(const bf16x8*)(w1l + off);
      }
#pragma unroll
      for (int mi = 0; mi < 4; ++mi) {
        bf16x8 ah = *(const bf16x8*)&Ah[(mi * 16 + c) * 72 + kk + q * 8];
        bf16x8 al = *(const bf16x8*)&Al[(mi * 16 + c) * 72 + kk + q * 8];
#pragma unroll
        for (int nt = 0; nt < 4; ++nt)
          acc[mi][nt] = __builtin_amdgcn_mfma_f32_16x16x32_bf16(ah, bh[nt], acc[mi][nt], 0, 0, 0);
#pragma unroll
        for (int nt = 0; nt < 4; ++nt)
          acc[mi][nt] = __builtin_amdgcn_mfma_f32_16x16x32_bf16(al, bh[nt], acc[mi][nt], 0, 0, 0);
#pragma unroll
        for (int nt = 0; nt < 4; ++nt)
          acc[mi][nt] = __builtin_amdgcn_mfma_f32_16x16x32_bf16(ah, bl[nt], acc[mi][nt], 0, 0, 0);
      }
    }
  }

  // epilogue: +b1, e_l/e_r partial dots
  float b1v[4], alv[4], arv[4];
#pragma unroll
  for (int nt = 0; nt < 4; ++nt) {
    int e = n0 + nt * 16 + c;
    b1v[nt] = b1[e];
    alv[nt] = a_w[e];
    arv[nt] = a_w[256 + e];
  }
  float epl[4][4] = {}, epr[4][4] = {};
#pragma unroll
  for (int nt = 0; nt < 4; ++nt)
#pragma unroll
    for (int mi = 0; mi < 4; ++mi)
#pragma unroll
      for (int reg = 0; reg < 4; ++reg) {
        float wv = acc[mi][nt][reg] + b1v[nt];
        acc[mi][nt][reg] = wv;
        epl[mi][reg] += wv * alv[nt];
        epr[mi][reg] += wv * arv[nt];
      }
#pragma unroll
  for (int off = 1; off < 16; off <<= 1)
#pragma unroll
    for (int mi = 0; mi < 4; ++mi)
#pragma unroll
      for (int reg = 0; reg < 4; ++reg) {
        epl[mi][reg] += __shfl_xor(epl[mi][reg], off);
        epr[mi][reg] += __shfl_xor(epr[mi][reg], off);
      }
  if (c == 0) {
#pragma unroll
    for (int mi = 0; mi < 4; ++mi)
#pragma unroll
      for (int reg = 0; reg < 4; ++reg) {
        epart[0][wave][mi * 16 + q * 4 + reg] = epl[mi][reg];
        epart[1][wave][mi * 16 + q * 4 + reg] = epr[mi][reg];
      }
  }
  __syncthreads(); // also guards MFMA-phase LDS reads before T overwrite
  if (t < 64) {
    e_l[row0 + t] = epart[0][0][t] + epart[0][1][t] + epart[0][2][t] + epart[0][3][t];
    e_r[row0 + t] = epart[1][0][t] + epart[1][1][t] + epart[1][2][t] + epart[1][3][t];
  }

  // transpose Wh tile -> bf16 Wh^T[e][s] in LDS, then coalesced-ish global write
  ushort* T = smem; // [256][72]
#pragma unroll
  for (int mi = 0; mi < 4; ++mi)
#pragma unroll
    for (int nt = 0; nt < 4; ++nt) {
      ushort4 h;
      ushort* hp = (ushort*)&h;
#pragma unroll
      for (int reg = 0; reg < 4; ++reg) hp[reg] = f2bf(acc[mi][nt][reg]);
      *(ushort4*)&T[(size_t)(n0 + nt * 16 + c) * 72 + mi * 16 + q * 4] = h;
    }
  __syncthreads();
  {
    const int b = row0 >> 8, s0 = row0 & 255;
    ushort* dst = whT + ((size_t)b * 256 + t) * 256 + s0;
#pragma unroll
    for (int j = 0; j < 8; ++j)
      *(uint4*)(dst + j * 8) = *(const uint4*)&T[t * 72 + j * 8];
  }
}

// ---------------------------------------------------------------------------
// Kernel 2: per (b, 64-row i-tile): scores -> exp (no max-subtract, safe:
// s <~ 25) -> unnormalized p as bf16 hi/lo in LDS -> MFMA p @ Wh^T ->
// divide by fp32 row-sum -> ELU -> out.
// ---------------------------------------------------------------------------
__global__ __launch_bounds__(256) void k_attn(const ushort* __restrict__ whT,
                                              const float* __restrict__ pos,
                                              const float* __restrict__ e_l,
                                              const float* __restrict__ e_r,
                                              const float* __restrict__ a_b,
                                              float* __restrict__ out) {
  __shared__ __align__(16) ushort ph[64 * 264];
  __shared__ __align__(16) ushort pl[64 * 264];
  __shared__ __align__(16) float er_s[256];
  __shared__ float el_s[64];
  __shared__ float rsum[64];

  const int t = threadIdx.x;
  const int wave = t >> 6, lane = t & 63;
  const int q = lane >> 4, c = lane & 15;
  const int b = blockIdx.y, i0 = blockIdx.x * 64;

  er_s[t] = e_r[b * 256 + t];
  if (t < 64) el_s[t] = e_l[b * 256 + i0 + t];
  __syncthreads();

  const float ab = a_b[0];
  const float* posb = pos + ((size_t)b * 256 + i0) * 256;
#pragma unroll 4
  for (int ii = 0; ii < 16; ++ii) {
    int i = ii * 4 + wave; // wave owns whole row i
    float4 pv = *(const float4*)(posb + (size_t)i * 256 + lane * 4);
    float el = el_s[i];
    float4 er = *(const float4*)&er_s[lane * 4];
    float s0 = el + er.x + ab; s0 = (s0 >= 0.f) ? s0 : NEG_SLOPE * s0; s0 += pv.x;
    float s1 = el + er.y + ab; s1 = (s1 >= 0.f) ? s1 : NEG_SLOPE * s1; s1 += pv.y;
    float s2 = el + er.z + ab; s2 = (s2 >= 0.f) ? s2 : NEG_SLOPE * s2; s2 += pv.z;
    float s3 = el + er.w + ab; s3 = (s3 >= 0.f) ? s3 : NEG_SLOPE * s3; s3 += pv.w;
    float e0 = __expf(s0), e1 = __expf(s1), e2 = __expf(s2), e3 = __expf(s3);
    float rs = e0 + e1 + e2 + e3;
#pragma unroll
    for (int off = 1; off < 64; off <<= 1) rs += __shfl_xor(rs, off);
    ushort4 h, l;
    ushort* hp = (ushort*)&h;
    ushort* lp = (ushort*)&l;
    hp[0] = f2bf(e0); lp[0] = f2bf(e0 - bf2f(hp[0]));
    hp[1] = f2bf(e1); lp[1] = f2bf(e1 - bf2f(hp[1]));
    hp[2] = f2bf(e2); lp[2] = f2bf(e2 - bf2f(hp[2]));
    hp[3] = f2bf(e3); lp[3] = f2bf(e3 - bf2f(hp[3]));
    *(ushort4*)&ph[i * 264 + lane * 4] = h;
    *(ushort4*)&pl[i * 264 + lane * 4] = l;
    if (lane == 0) rsum[i] = rs;
  }
  __syncthreads();

  // aggregation: agg(64x256) = p(64x256) @ Wh^T-asB(256x256), 2-term split on p
  f32x4 acc[4][4];
#pragma unroll
  for (int mi = 0; mi < 4; ++mi)
#pragma unroll
    for (int nt = 0; nt < 4; ++nt) acc[mi][nt] = (f32x4){0.f, 0.f, 0.f, 0.f};

  const int n0 = wave * 64;
  const ushort* wb = whT + (size_t)b * 65536;
  for (int kk = 0; kk < 256; kk += 32) {
    bf16x8 bfr[4];
#pragma unroll
    for (int nt = 0; nt < 4; ++nt)
      bfr[nt] = *(const bf16x8*)(wb + (size_t)(n0 + nt * 16 + c) * 256 + kk + q * 8);
#pragma unroll
    for (int mi = 0; mi < 4; ++mi) {
      bf16x8 ah = *(const bf16x8*)&ph[(mi * 16 + c) * 264 + kk + q * 8];
      bf16x8 al = *(const bf16x8*)&pl[(mi * 16 + c) * 264 + kk + q * 8];
#pragma unroll
      for (int nt = 0; nt < 4; ++nt)
        acc[mi][nt] = __builtin_amdgcn_mfma_f32_16x16x32_bf16(ah, bfr[nt], acc[mi][nt], 0, 0, 0);
#pragma unroll
      for (int nt = 0; nt < 4; ++nt)
        acc[mi][nt] = __builtin_amdgcn_mfma_f32_16x16x32_bf16(al, bfr[nt], acc[mi][nt], 0, 0, 0);
    }
  }

  // epilogue: normalize by row-sum, ELU, store
  float* outb = out + ((size_t)b * 256 + i0) * 256;
#pragma unroll
  for (int mi = 0; mi < 4; ++mi) {
    float alpha[4];
#pragma unroll
    for (int reg = 0; reg < 4; ++reg) alpha[reg] = 1.0f / rsum[mi * 16 + q * 4 + reg];
#pragma unroll
    for (int nt = 0; nt < 4; ++nt)
#pragma unroll
      for (int reg = 0; reg < 4; ++reg) {
        float v = acc[mi][nt][reg] * alpha[reg];
        v = (v > 0.f) ? v : (__expf(v) - 1.0f);
        outb[(size_t)(mi * 16 + q * 4 + reg) * 256 + n0 + nt * 16 + c] = v;
      }
  }
}

// ---------------------------------------------------------------------------
extern "C" void kernel_launch(void* const* d_in, const int* in_sizes, int n_in,
                              void* d_out, int out_size, void* d_ws, size_t ws_size,
                              hipStream_t stream) {
  const float* x   = (const float*)d_in[0];
  const float* pos = (const float*)d_in[1];
  const float* w1  = (const float*)d_in[2];
  const float* b1  = (const float*)d_in[3];
  const float* a_w = (const float*)d_in[4];
  const float* a_b = (const float*)d_in[5];
  float* out = (float*)d_out;

  ushort* w1h = (ushort*)d_ws;                 // 65536
  ushort* w1l = w1h + 65536;                   // 65536
  ushort* whT = w1l + 65536;                   // 512*256*256 = 33554432 (64 MB)
  float*  e_l = (float*)(whT + (size_t)33554432); // 131072
  float*  e_r = e_l + Mn;                      // 131072

  k_prep<<<dim3(256), dim3(256), 0, stream>>>(w1, w1h, w1l);
  k_gemm1<<<dim3(Mn / 64), dim3(256), 0, stream>>>(x, w1h, w1l, b1, a_w, whT, e_l, e_r);
  k_attn<<<dim3(Sn / 64, Bn), dim3(256), 0, stream>>>(whT, pos, e_l, e_r, a_b, out);
}

// Round 3
// 412.376 us; speedup vs baseline: 1.8256x; 1.0883x over previous
//
#include <hip/hip_runtime.h>
#include <math.h>

#define NEG_SLOPE 0.1f

constexpr int Bn = 512;
constexpr int Sn = 256;
constexpr int Dn = 256;
constexpr int Mn = Bn * Sn; // 131072

typedef short bf16x8 __attribute__((ext_vector_type(8))); // 8 bf16 in 4 VGPRs
typedef float f32x4 __attribute__((ext_vector_type(4)));

__device__ inline ushort f2bf(float f) { // round-to-nearest-even bf16 bits
  uint u = __float_as_uint(f);
  uint r = u + 0x7FFFu + ((u >> 16) & 1u);
  return (ushort)(r >> 16);
}

// ---------------------------------------------------------------------------
// Kernel 0: W1 (fp32 [e][d]) -> bf16 (hi only; lo terms contribute ~1e-3,
// far below the 0.008 bf16-storage floor of whT).
// ---------------------------------------------------------------------------
__global__ __launch_bounds__(256) void k_prep(const float* __restrict__ w1,
                                              ushort* __restrict__ w1h) {
  int idx = blockIdx.x * 256 + threadIdx.x;
  w1h[idx] = f2bf(w1[idx]);
}

// ---------------------------------------------------------------------------
// Kernel 0b: v_l[d] = sum_e W1[e][d]*a_l[e]; v_r likewise; c_l = b1.a_l etc.
// vlr[0:256]=v_l, [256:512]=v_r, [512]=c_l, [513]=c_r. vlr pre-zeroed.
// e_l[m] = x[m,:].v_l + c_l  EXACTLY in fp32 (softmax exponent precision).
// ---------------------------------------------------------------------------
__global__ __launch_bounds__(256) void k_vec(const float* __restrict__ w1,
                                             const float* __restrict__ a_w,
                                             const float* __restrict__ b1,
                                             float* __restrict__ vlr) {
  int d = threadIdx.x;
  int e0 = blockIdx.x * 32;
  float vl = 0.f, vr = 0.f;
  for (int e = e0; e < e0 + 32; ++e) {
    float w = w1[(size_t)e * 256 + d];
    vl += w * a_w[e];
    vr += w * a_w[256 + e];
  }
  atomicAdd(&vlr[d], vl);
  atomicAdd(&vlr[256 + d], vr);
  if (blockIdx.x == 0) {
    float pl = b1[d] * a_w[d], pr = b1[d] * a_w[256 + d];
#pragma unroll
    for (int o = 1; o < 64; o <<= 1) {
      pl += __shfl_xor(pl, o);
      pr += __shfl_xor(pr, o);
    }
    if ((threadIdx.x & 63) == 0) {
      atomicAdd(&vlr[512], pl);
      atomicAdd(&vlr[513], pr);
    }
  }
}

// ---------------------------------------------------------------------------
// Kernel 1: Wh = x @ W1^T + b1, single bf16 MFMA term.
// Fused: exact fp32 e_l/e_r dots (from the fp32 staging loads, against v_l/v_r)
// and bf16 Wh^T write via LDS transpose ([b][d][s] = aggregation B layout).
// ---------------------------------------------------------------------------
__global__ __launch_bounds__(256) void k_gemm1(const float* __restrict__ x,
                                               const ushort* __restrict__ w1h,
                                               const float* __restrict__ b1,
                                               const float* __restrict__ vlr,
                                               ushort* __restrict__ whT,
                                               float* __restrict__ e_l,
                                               float* __restrict__ e_r) {
  __shared__ __align__(16) ushort smem[256 * 72]; // union: Ah[64][72] | T[256][72]
  __shared__ float vl_s[256], vr_s[256];
  ushort* Ah = smem;
  ushort* T = smem;

  const int t = threadIdx.x;
  const int wave = t >> 6, lane = t & 63;
  const int q = lane >> 4, c = lane & 15;
  const int row0 = blockIdx.x * 64;
  const int n0 = wave * 64;

  vl_s[t] = vlr[t];
  vr_s[t] = vlr[256 + t];

  f32x4 acc[4][4];
#pragma unroll
  for (int mi = 0; mi < 4; ++mi)
#pragma unroll
    for (int nt = 0; nt < 4; ++nt) acc[mi][nt] = (f32x4){0.f, 0.f, 0.f, 0.f};

  const int r = t >> 2;         // 0..63 staging row
  const int kq = (t & 3) << 4;  // 0,16,32,48
  const float* xrow = x + (size_t)(row0 + r) * 256 + kq;
  float sl = 0.f, sr = 0.f;

  for (int k0 = 0; k0 < 256; k0 += 64) {
    float4 v0 = *(const float4*)(xrow + k0 + 0);
    float4 v1 = *(const float4*)(xrow + k0 + 4);
    float4 v2 = *(const float4*)(xrow + k0 + 8);
    float4 v3 = *(const float4*)(xrow + k0 + 12);
    __syncthreads(); // prior iter's LDS reads done (and vl_s visible, 1st iter)
    {
      float vv[16] = {v0.x, v0.y, v0.z, v0.w, v1.x, v1.y, v1.z, v1.w,
                      v2.x, v2.y, v2.z, v2.w, v3.x, v3.y, v3.z, v3.w};
#pragma unroll
      for (int j = 0; j < 16; ++j) {
        sl += vv[j] * vl_s[k0 + kq + j];
        sr += vv[j] * vr_s[k0 + kq + j];
      }
#pragma unroll
      for (int j = 0; j < 4; ++j) {
        ushort4 h;
        ushort* hp = (ushort*)&h;
#pragma unroll
        for (int e = 0; e < 4; ++e) hp[e] = f2bf(vv[j * 4 + e]);
        *(ushort4*)&Ah[r * 72 + kq + j * 4] = h;
      }
    }
    __syncthreads();

#pragma unroll
    for (int kk = 0; kk < 64; kk += 32) {
      bf16x8 bh[4];
#pragma unroll
      for (int nt = 0; nt < 4; ++nt)
        bh[nt] = *(const bf16x8*)(w1h + (size_t)(n0 + nt * 16 + c) * 256 + (k0 + kk) + q * 8);
#pragma unroll
      for (int mi = 0; mi < 4; ++mi) {
        bf16x8 ah = *(const bf16x8*)&Ah[(mi * 16 + c) * 72 + kk + q * 8];
#pragma unroll
        for (int nt = 0; nt < 4; ++nt)
          acc[mi][nt] = __builtin_amdgcn_mfma_f32_16x16x32_bf16(ah, bh[nt], acc[mi][nt], 0, 0, 0);
      }
    }
  }

  // exact fp32 e_l/e_r: reduce the 4 k-subranges (lanes t, t^1, t^2 same wave)
  sl += __shfl_xor(sl, 1); sl += __shfl_xor(sl, 2);
  sr += __shfl_xor(sr, 1); sr += __shfl_xor(sr, 2);
  if ((t & 3) == 0) {
    e_l[row0 + r] = sl + vlr[512];
    e_r[row0 + r] = sr + vlr[513];
  }

  // +b1, transpose to Wh^T bf16 via LDS, coalesced global write
  float b1v[4];
#pragma unroll
  for (int nt = 0; nt < 4; ++nt) b1v[nt] = b1[n0 + nt * 16 + c];
  __syncthreads(); // Ah reads done before T overwrite (union)
#pragma unroll
  for (int mi = 0; mi < 4; ++mi)
#pragma unroll
    for (int nt = 0; nt < 4; ++nt) {
      ushort4 h;
      ushort* hp = (ushort*)&h;
#pragma unroll
      for (int reg = 0; reg < 4; ++reg) hp[reg] = f2bf(acc[mi][nt][reg] + b1v[nt]);
      *(ushort4*)&T[(size_t)(n0 + nt * 16 + c) * 72 + mi * 16 + q * 4] = h;
    }
  __syncthreads();
  {
    const int b = row0 >> 8, s0 = row0 & 255;
    ushort* dst = whT + ((size_t)b * 256 + t) * 256 + s0;
#pragma unroll
    for (int j = 0; j < 8; ++j)
      *(uint4*)(dst + j * 8) = *(const uint4*)&T[t * 72 + j * 8];
  }
}

// ---------------------------------------------------------------------------
// Kernel 2: per (b, 64-row i-tile): scores -> exp (no max-pass; s <~ 25)
// -> unnormalized p bf16 (hi only) in LDS -> 1-term MFMA p @ Wh^T ->
// normalize by fp32 row-sum -> ELU -> out.
// ---------------------------------------------------------------------------
__global__ __launch_bounds__(256) void k_attn(const ushort* __restrict__ whT,
                                              const float* __restrict__ pos,
                                              const float* __restrict__ e_l,
                                              const float* __restrict__ e_r,
                                              const float* __restrict__ a_b,
                                              float* __restrict__ out) {
  __shared__ __align__(16) ushort ph[64 * 264]; // 33.8 KB
  __shared__ __align__(16) float er_s[256];
  __shared__ float el_s[64];
  __shared__ float rsum[64];

  const int t = threadIdx.x;
  const int wave = t >> 6, lane = t & 63;
  const int q = lane >> 4, c = lane & 15;
  const int b = blockIdx.y, i0 = blockIdx.x * 64;

  er_s[t] = e_r[b * 256 + t];
  if (t < 64) el_s[t] = e_l[b * 256 + i0 + t];
  __syncthreads();

  const float ab = a_b[0];
  const float* posb = pos + ((size_t)b * 256 + i0) * 256;
#pragma unroll 4
  for (int ii = 0; ii < 16; ++ii) {
    int i = ii * 4 + wave; // wave owns whole row i
    float4 pv = *(const float4*)(posb + (size_t)i * 256 + lane * 4);
    float el = el_s[i];
    float4 er = *(const float4*)&er_s[lane * 4];
    float s0 = el + er.x + ab; s0 = (s0 >= 0.f) ? s0 : NEG_SLOPE * s0; s0 += pv.x;
    float s1 = el + er.y + ab; s1 = (s1 >= 0.f) ? s1 : NEG_SLOPE * s1; s1 += pv.y;
    float s2 = el + er.z + ab; s2 = (s2 >= 0.f) ? s2 : NEG_SLOPE * s2; s2 += pv.z;
    float s3 = el + er.w + ab; s3 = (s3 >= 0.f) ? s3 : NEG_SLOPE * s3; s3 += pv.w;
    float e0 = __expf(s0), e1 = __expf(s1), e2 = __expf(s2), e3 = __expf(s3);
    float rs = e0 + e1 + e2 + e3;
#pragma unroll
    for (int off = 1; off < 64; off <<= 1) rs += __shfl_xor(rs, off);
    ushort4 h;
    ushort* hp = (ushort*)&h;
    hp[0] = f2bf(e0); hp[1] = f2bf(e1); hp[2] = f2bf(e2); hp[3] = f2bf(e3);
    *(ushort4*)&ph[i * 264 + lane * 4] = h;
    if (lane == 0) rsum[i] = rs;
  }
  __syncthreads();

  f32x4 acc[4][4];
#pragma unroll
  for (int mi = 0; mi < 4; ++mi)
#pragma unroll
    for (int nt = 0; nt < 4; ++nt) acc[mi][nt] = (f32x4){0.f, 0.f, 0.f, 0.f};

  const int n0 = wave * 64;
  const ushort* wb = whT + (size_t)b * 65536;
  for (int kk = 0; kk < 256; kk += 32) {
    bf16x8 bfr[4];
#pragma unroll
    for (int nt = 0; nt < 4; ++nt)
      bfr[nt] = *(const bf16x8*)(wb + (size_t)(n0 + nt * 16 + c) * 256 + kk + q * 8);
#pragma unroll
    for (int mi = 0; mi < 4; ++mi) {
      bf16x8 ah = *(const bf16x8*)&ph[(mi * 16 + c) * 264 + kk + q * 8];
#pragma unroll
      for (int nt = 0; nt < 4; ++nt)
        acc[mi][nt] = __builtin_amdgcn_mfma_f32_16x16x32_bf16(ah, bfr[nt], acc[mi][nt], 0, 0, 0);
    }
  }

  // epilogue: normalize, ELU, store
  float* outb = out + ((size_t)b * 256 + i0) * 256;
#pragma unroll
  for (int mi = 0; mi < 4; ++mi) {
    float alpha[4];
#pragma unroll
    for (int reg = 0; reg < 4; ++reg) alpha[reg] = 1.0f / rsum[mi * 16 + q * 4 + reg];
#pragma unroll
    for (int nt = 0; nt < 4; ++nt)
#pragma unroll
      for (int reg = 0; reg < 4; ++reg) {
        float v = acc[mi][nt][reg] * alpha[reg];
        v = (v > 0.f) ? v : (__expf(v) - 1.0f);
        outb[(size_t)(mi * 16 + q * 4 + reg) * 256 + n0 + nt * 16 + c] = v;
      }
  }
}

// ---------------------------------------------------------------------------
extern "C" void kernel_launch(void* const* d_in, const int* in_sizes, int n_in,
                              void* d_out, int out_size, void* d_ws, size_t ws_size,
                              hipStream_t stream) {
  const float* x   = (const float*)d_in[0];
  const float* pos = (const float*)d_in[1];
  const float* w1  = (const float*)d_in[2];
  const float* b1  = (const float*)d_in[3];
  const float* a_w = (const float*)d_in[4];
  const float* a_b = (const float*)d_in[5];
  float* out = (float*)d_out;

  ushort* w1h = (ushort*)d_ws;                    // 65536 ushort (128 KB)
  ushort* whT = w1h + 65536;                      // 33554432 ushort (64 MB)
  float*  e_l = (float*)(whT + (size_t)33554432); // 131072
  float*  e_r = e_l + Mn;                         // 131072
  float*  vlr = e_r + Mn;                         // 514 floats

  hipMemsetAsync(vlr, 0, 514 * sizeof(float), stream);
  k_prep<<<dim3(256), dim3(256), 0, stream>>>(w1, w1h);
  k_vec<<<dim3(8), dim3(256), 0, stream>>>(w1, a_w, b1, vlr);
  k_gemm1<<<dim3(Mn / 64), dim3(256), 0, stream>>>(x, w1h, b1, vlr, whT, e_l, e_r);
  k_attn<<<dim3(Sn / 64, Bn), dim3(256), 0, stream>>>(whT, pos, e_l, e_r, a_b, out);
}